// Round 1
// baseline (1617.137 us; speedup 1.0000x reference)
//
#include <hip/hip_runtime.h>
#include <math.h>

// Problem constants (fixed by the reference):
#define MTOT 36864      // N_SHOTS * N_SAMPLES; also == NPIX*NPIX (192^2)
#define NPIX 192
#define SPLITS 128
#define KPB (MTOT / SPLITS)   // 288 m-values per split-K block

// ---------------------------------------------------------------------------
// Precompute A (row-major [m][x]) and B (row-major [m][y]).
// Phase reduced mod 1 revolution in double, then float sin/cos of arg in [-pi,pi].
__global__ void precomp_ab_k(const float* __restrict__ traj,
                             float* __restrict__ Ar, float* __restrict__ Ai,
                             float* __restrict__ Br, float* __restrict__ Bi) {
    const int m = blockIdx.x;
    const int y = threadIdx.x;                       // 0..191 (pixel coord)
    const float kx = traj[2 * m], ky = traj[2 * m + 1];
    const double p = (double)y - 96.0;
    double r = (double)kx * p; r -= rint(r);
    float t = (float)(r * 6.283185307179586477);
    Ar[(size_t)m * NPIX + y] = cosf(t);
    Ai[(size_t)m * NPIX + y] = -sinf(t);
    r = (double)ky * p; r -= rint(r);
    t = (float)(r * 6.283185307179586477);
    Br[(size_t)m * NPIX + y] = cosf(t);
    Bi[(size_t)m * NPIX + y] = -sinf(t);
}

// B transposed: BT [y][m], m contiguous (coalesced writes).
__global__ void precomp_bt_k(const float* __restrict__ traj,
                             float* __restrict__ BTr, float* __restrict__ BTi) {
    const int m = blockIdx.x * 256 + threadIdx.x;
    const int y = blockIdx.y;
    const float ky = traj[2 * m + 1];
    double r = (double)ky * ((double)y - 96.0); r -= rint(r);
    const float t = (float)(r * 6.283185307179586477);
    BTr[(size_t)y * MTOT + m] = cosf(t);
    BTi[(size_t)y * MTOT + m] = -sinf(t);
}

__global__ void winit_k(float* __restrict__ wr, float* __restrict__ wi) {
    const int m = blockIdx.x * 256 + threadIdx.x;
    wr[m] = 1.0f; wi[m] = 0.0f;
}

// Transpose input image planes into gT[y][x] (re, im).
__global__ void imgt_k(const float* __restrict__ xin,
                       float* __restrict__ gTr, float* __restrict__ gTi) {
    const int y = blockIdx.x;        // 0..191
    const int x = threadIdx.x;       // 0..191
    gTr[y * NPIX + x] = xin[x * NPIX + y];
    gTi[y * NPIX + x] = xin[MTOT + x * NPIX + y];
}

// ---------------------------------------------------------------------------
// Adjoint GEMM: out[x,y] (+)= sum_m conj(A[m,x]) * d[m] * conj(B[m,y])
// 64x64 output tile per block, split-K over blockIdx.z, fp32 atomicAdd epilogue.
// u[m,y] = d[m]*conj(B[m,y]) computed on the fly during staging.
__global__ __launch_bounds__(256) void adj_gemm_k(
    const float* __restrict__ Ar, const float* __restrict__ Ai,
    const float* __restrict__ Br, const float* __restrict__ Bi,
    const float* __restrict__ dr, const float* __restrict__ di,
    float* __restrict__ outRe, float* __restrict__ outIm, const int transp)
{
    __shared__ __align__(16) float sAr[32][68], sAi[32][68], sUr[32][68], sUi[32][68];
    const int tid = threadIdx.x;
    const int tx = tid & 15, ty = tid >> 4;          // tx -> x cols, ty -> y cols
    const int x0 = blockIdx.x * 64, y0 = blockIdx.y * 64;
    const int mbase = blockIdx.z * KPB;
    const int lr = tid >> 3;                         // 0..31 staging row (m)
    const int lc = (tid & 7) * 4;                    // 0..28 staging col

    float cr[4][4] = {{0.f}}, ci[4][4] = {{0.f}};

    for (int kk = 0; kk < KPB; kk += 32) {
        const int mrow_i = mbase + kk + lr;
        const size_t mrow = (size_t)mrow_i * NPIX;
        float4 v;
        v = *(const float4*)(Ar + mrow + x0 + lc);      *(float4*)&sAr[lr][lc]      = v;
        v = *(const float4*)(Ar + mrow + x0 + lc + 32); *(float4*)&sAr[lr][lc + 32] = v;
        v = *(const float4*)(Ai + mrow + x0 + lc);      *(float4*)&sAi[lr][lc]      = v;
        v = *(const float4*)(Ai + mrow + x0 + lc + 32); *(float4*)&sAi[lr][lc + 32] = v;

        const float wre = dr[mrow_i];
        const float wim = di[mrow_i];
        const float4 br0 = *(const float4*)(Br + mrow + y0 + lc);
        const float4 br1 = *(const float4*)(Br + mrow + y0 + lc + 32);
        const float4 bq0 = *(const float4*)(Bi + mrow + y0 + lc);
        const float4 bq1 = *(const float4*)(Bi + mrow + y0 + lc + 32);
        float4 u;
        // u_re = wre*Br + wim*Bi ; u_im = wim*Br - wre*Bi
        u.x = wre*br0.x + wim*bq0.x; u.y = wre*br0.y + wim*bq0.y;
        u.z = wre*br0.z + wim*bq0.z; u.w = wre*br0.w + wim*bq0.w;
        *(float4*)&sUr[lr][lc] = u;
        u.x = wre*br1.x + wim*bq1.x; u.y = wre*br1.y + wim*bq1.y;
        u.z = wre*br1.z + wim*bq1.z; u.w = wre*br1.w + wim*bq1.w;
        *(float4*)&sUr[lr][lc + 32] = u;
        u.x = wim*br0.x - wre*bq0.x; u.y = wim*br0.y - wre*bq0.y;
        u.z = wim*br0.z - wre*bq0.z; u.w = wim*br0.w - wre*bq0.w;
        *(float4*)&sUi[lr][lc] = u;
        u.x = wim*br1.x - wre*bq1.x; u.y = wim*br1.y - wre*bq1.y;
        u.z = wim*br1.z - wre*bq1.z; u.w = wim*br1.w - wre*bq1.w;
        *(float4*)&sUi[lr][lc + 32] = u;

        __syncthreads();
        #pragma unroll 8
        for (int k = 0; k < 32; ++k) {
            const float2 axr0 = *(const float2*)&sAr[k][2 * tx];
            const float2 axr1 = *(const float2*)&sAr[k][2 * tx + 32];
            const float2 axi0 = *(const float2*)&sAi[k][2 * tx];
            const float2 axi1 = *(const float2*)&sAi[k][2 * tx + 32];
            const float2 uyr0 = *(const float2*)&sUr[k][2 * ty];
            const float2 uyr1 = *(const float2*)&sUr[k][2 * ty + 32];
            const float2 uyi0 = *(const float2*)&sUi[k][2 * ty];
            const float2 uyi1 = *(const float2*)&sUi[k][2 * ty + 32];
            const float axr[4] = {axr0.x, axr0.y, axr1.x, axr1.y};
            const float axi[4] = {axi0.x, axi0.y, axi1.x, axi1.y};
            const float uyr[4] = {uyr0.x, uyr0.y, uyr1.x, uyr1.y};
            const float uyi[4] = {uyi0.x, uyi0.y, uyi1.x, uyi1.y};
            #pragma unroll
            for (int i = 0; i < 4; ++i) {
                #pragma unroll
                for (int j = 0; j < 4; ++j) {
                    // conj(A)*u = (ar*ur + ai*ui) + i(ar*ui - ai*ur)
                    cr[i][j] += axr[i]*uyr[j] + axi[i]*uyi[j];
                    ci[i][j] += axr[i]*uyi[j] - axi[i]*uyr[j];
                }
            }
        }
        __syncthreads();
    }

    #pragma unroll
    for (int i = 0; i < 4; ++i) {
        const int x = x0 + 2 * tx + (i & 1) + (i >> 1) * 32;
        #pragma unroll
        for (int j = 0; j < 4; ++j) {
            const int y = y0 + 2 * ty + (j & 1) + (j >> 1) * 32;
            const size_t idx = transp ? ((size_t)y * NPIX + x) : ((size_t)x * NPIX + y);
            atomicAdd(outRe + idx, cr[i][j]);
            atomicAdd(outIm + idx, ci[i][j]);
        }
    }
}

// ---------------------------------------------------------------------------
// Forward-t GEMM: t[m,x] = sum_y B[m,y]*g[x,y], using BT[y][m] and gT[y][x].
// 64(m) x 64(x) tile per block; K=192 full loop; direct float2 stores.
__global__ __launch_bounds__(256) void fwd_gemm_k(
    const float* __restrict__ BTr, const float* __restrict__ BTi,
    const float* __restrict__ gTr, const float* __restrict__ gTi,
    float* __restrict__ tre, float* __restrict__ tim)
{
    __shared__ __align__(16) float sBr[32][68], sBi[32][68], sGr[32][68], sGi[32][68];
    const int tid = threadIdx.x;
    const int tx = tid & 15, ty = tid >> 4;          // tx -> x cols, ty -> m rows
    const int m0 = blockIdx.x * 64, x0 = blockIdx.y * 64;
    const int lr = tid >> 3, lc = (tid & 7) * 4;

    float t_r[4][4] = {{0.f}}, t_i[4][4] = {{0.f}};

    for (int kc = 0; kc < NPIX; kc += 32) {
        const int yk = kc + lr;
        float4 v;
        v = *(const float4*)(BTr + (size_t)yk * MTOT + m0 + lc);      *(float4*)&sBr[lr][lc]      = v;
        v = *(const float4*)(BTr + (size_t)yk * MTOT + m0 + lc + 32); *(float4*)&sBr[lr][lc + 32] = v;
        v = *(const float4*)(BTi + (size_t)yk * MTOT + m0 + lc);      *(float4*)&sBi[lr][lc]      = v;
        v = *(const float4*)(BTi + (size_t)yk * MTOT + m0 + lc + 32); *(float4*)&sBi[lr][lc + 32] = v;
        v = *(const float4*)(gTr + (size_t)yk * NPIX + x0 + lc);      *(float4*)&sGr[lr][lc]      = v;
        v = *(const float4*)(gTr + (size_t)yk * NPIX + x0 + lc + 32); *(float4*)&sGr[lr][lc + 32] = v;
        v = *(const float4*)(gTi + (size_t)yk * NPIX + x0 + lc);      *(float4*)&sGi[lr][lc]      = v;
        v = *(const float4*)(gTi + (size_t)yk * NPIX + x0 + lc + 32); *(float4*)&sGi[lr][lc + 32] = v;

        __syncthreads();
        #pragma unroll 8
        for (int k = 0; k < 32; ++k) {
            const float2 bmr0 = *(const float2*)&sBr[k][2 * ty];
            const float2 bmr1 = *(const float2*)&sBr[k][2 * ty + 32];
            const float2 bmi0 = *(const float2*)&sBi[k][2 * ty];
            const float2 bmi1 = *(const float2*)&sBi[k][2 * ty + 32];
            const float2 gxr0 = *(const float2*)&sGr[k][2 * tx];
            const float2 gxr1 = *(const float2*)&sGr[k][2 * tx + 32];
            const float2 gxi0 = *(const float2*)&sGi[k][2 * tx];
            const float2 gxi1 = *(const float2*)&sGi[k][2 * tx + 32];
            const float bmr[4] = {bmr0.x, bmr0.y, bmr1.x, bmr1.y};
            const float bmi[4] = {bmi0.x, bmi0.y, bmi1.x, bmi1.y};
            const float gxr[4] = {gxr0.x, gxr0.y, gxr1.x, gxr1.y};
            const float gxi[4] = {gxi0.x, gxi0.y, gxi1.x, gxi1.y};
            #pragma unroll
            for (int i = 0; i < 4; ++i) {
                #pragma unroll
                for (int j = 0; j < 4; ++j) {
                    t_r[i][j] += bmr[i]*gxr[j] - bmi[i]*gxi[j];
                    t_i[i][j] += bmr[i]*gxi[j] + bmi[i]*gxr[j];
                }
            }
        }
        __syncthreads();
    }

    #pragma unroll
    for (int i = 0; i < 4; ++i) {
        const size_t mrow = (size_t)(m0 + 2 * ty + (i & 1) + (i >> 1) * 32) * NPIX;
        *(float2*)(tre + mrow + x0 + 2 * tx)      = make_float2(t_r[i][0], t_r[i][1]);
        *(float2*)(tre + mrow + x0 + 2 * tx + 32) = make_float2(t_r[i][2], t_r[i][3]);
        *(float2*)(tim + mrow + x0 + 2 * tx)      = make_float2(t_i[i][0], t_i[i][1]);
        *(float2*)(tim + mrow + x0 + 2 * tx + 32) = make_float2(t_i[i][2], t_i[i][3]);
    }
}

// ---------------------------------------------------------------------------
// Row dot: out[m] = sum_x A[m,x]*t[m,x]; if wr!=null, scale by |w[m]| (forward path).
__global__ void rowdot_k(const float* __restrict__ Ar, const float* __restrict__ Ai,
                         const float* __restrict__ tre, const float* __restrict__ tim,
                         const float* __restrict__ wr, const float* __restrict__ wi,
                         float* __restrict__ ore, float* __restrict__ oim)
{
    const int lane = threadIdx.x & 63;
    const int m = blockIdx.x * 4 + (threadIdx.x >> 6);
    const size_t row = (size_t)m * NPIX;
    float sre = 0.f, sim = 0.f;
    #pragma unroll
    for (int xx = 0; xx < 3; ++xx) {
        const int x = lane + xx * 64;
        const float ar = Ar[row + x], ai = Ai[row + x];
        const float tr = tre[row + x], ti = tim[row + x];
        sre += ar * tr - ai * ti;
        sim += ar * ti + ai * tr;
    }
    #pragma unroll
    for (int off = 32; off > 0; off >>= 1) {
        sre += __shfl_down(sre, off);
        sim += __shfl_down(sim, off);
    }
    if (lane == 0) {
        if (wr != nullptr) {
            const float mag = sqrtf(wr[m] * wr[m] + wi[m] * wi[m]);
            sre *= mag; sim *= mag;
        }
        ore[m] = sre; oim[m] = sim;
    }
}

// w <- w / max(|q|, 1e-20)
__global__ void wupdate_k(float* __restrict__ wr, float* __restrict__ wi,
                          const float* __restrict__ qre, const float* __restrict__ qim) {
    const int m = blockIdx.x * 256 + threadIdx.x;
    float den = sqrtf(qre[m] * qre[m] + qim[m] * qim[m]);
    den = fmaxf(den, 1e-20f);
    wr[m] /= den; wi[m] /= den;
}

// ---------------------------------------------------------------------------
extern "C" void kernel_launch(void* const* d_in, const int* in_sizes, int n_in,
                              void* d_out, int out_size, void* d_ws, size_t ws_size,
                              hipStream_t stream)
{
    const float* xin  = (const float*)d_in[0];   // (2,192,192)
    const float* traj = (const float*)d_in[1];   // (36864,2)
    float* out = (float*)d_out;                  // (2,192,192)

    float* p = (float*)d_ws;
    const size_t PLANE = (size_t)MTOT * NPIX;    // 7,077,888 floats
    float* Ar   = p; p += PLANE;
    float* Ai   = p; p += PLANE;
    float* Br   = p; p += PLANE;
    float* Bi   = p; p += PLANE;
    float* BTr  = p; p += PLANE;
    float* BTi  = p; p += PLANE;
    float* tre  = p; p += PLANE;
    float* tim_ = p; p += PLANE;
    float* ImTr = p; p += MTOT;   // 192x192 == MTOT elements (coincidence of sizes)
    float* ImTi = p; p += MTOT;
    float* gTr  = p; p += MTOT;
    float* gTi  = p; p += MTOT;
    float* wrp  = p; p += MTOT;
    float* wip  = p; p += MTOT;
    float* qre  = p; p += MTOT;
    float* qim  = p; p += MTOT;
    float* dre  = p; p += MTOT;
    float* dim_ = p; p += MTOT;

    // Output accumulated via atomics — zero it (harness poisons with 0xAA).
    hipMemsetAsync(d_out, 0, sizeof(float) * 2 * MTOT, stream);

    precomp_ab_k<<<MTOT, NPIX, 0, stream>>>(traj, Ar, Ai, Br, Bi);
    precomp_bt_k<<<dim3(MTOT / 256, NPIX), 256, 0, stream>>>(traj, BTr, BTi);
    winit_k<<<MTOT / 256, 256, 0, stream>>>(wrp, wip);

    // Pipe-Menon density iterations (3x): q = op(adj(w)); w /= max(|q|,1e-20)
    for (int it = 0; it < 3; ++it) {
        hipMemsetAsync(ImTr, 0, sizeof(float) * 2 * MTOT, stream);  // ImTr+ImTi contiguous
        adj_gemm_k<<<dim3(3, 3, SPLITS), 256, 0, stream>>>(Ar, Ai, Br, Bi, wrp, wip,
                                                           ImTr, ImTi, /*transp=*/1);
        fwd_gemm_k<<<dim3(MTOT / 64, 3), 256, 0, stream>>>(BTr, BTi, ImTr, ImTi, tre, tim_);
        rowdot_k<<<MTOT / 4, 256, 0, stream>>>(Ar, Ai, tre, tim_, nullptr, nullptr, qre, qim);
        wupdate_k<<<MTOT / 256, 256, 0, stream>>>(wrp, wip, qre, qim);
    }

    // Forward NUFFT on the input image, scale by |w|, final adjoint -> output.
    imgt_k<<<NPIX, NPIX, 0, stream>>>(xin, gTr, gTi);
    fwd_gemm_k<<<dim3(MTOT / 64, 3), 256, 0, stream>>>(BTr, BTi, gTr, gTi, tre, tim_);
    rowdot_k<<<MTOT / 4, 256, 0, stream>>>(Ar, Ai, tre, tim_, wrp, wip, dre, dim_);
    adj_gemm_k<<<dim3(3, 3, SPLITS), 256, 0, stream>>>(Ar, Ai, Br, Bi, dre, dim_,
                                                       out, out + MTOT, /*transp=*/0);
}

// Round 2
// 832.488 us; speedup vs baseline: 1.9425x; 1.9425x over previous
//
#include <hip/hip_runtime.h>
#include <math.h>

// Radial NUFFT + Pipe-Menon density compensation, MI355X (gfx950).
// All 8 big complex GEMMs run on bf16 MFMA (16x16x32) with 2-term hi/lo split
// (3 products: hi*hi + hi*lo + lo*hi -> ~2^-17 per-product relative error).
// Phasor operands are synthesized IN REGISTERS via v_sin/v_cos (revolutions,
// transcendental pipe overlaps the matrix pipe) -> no A/B matrices in HBM,
// no LDS staging, no K-loop barriers.

#define MTOT 36864      // N_SHOTS*N_SAMPLES == NPIX*NPIX
#define NPIX 192
#define SPLITS 128
#define MPS (MTOT / SPLITS)     // 288 m per split
#define ADJ_CHUNKS (MPS / 16)   // 18 chunks of 32 K (K = 2*M re/im-stacked)

typedef __attribute__((ext_vector_type(8))) short s16x8;
typedef __attribute__((ext_vector_type(4))) float f32x4;
typedef __attribute__((ext_vector_type(4))) unsigned u32x4;

__device__ __forceinline__ f32x4 mfma_bf16(u32x4 a, u32x4 b, f32x4 c) {
    return __builtin_amdgcn_mfma_f32_16x16x32_bf16(
        __builtin_bit_cast(s16x8, a), __builtin_bit_cast(s16x8, b), c, 0, 0, 0);
}

// Split (a,b) into packed bf16 pairs: hi = (bf16(a) | bf16(b)<<16), lo = residuals.
// Round-half-up on the hi keeps |lo| <= 2^-9|x|; lo quantization error ~2^-17|x|.
__device__ __forceinline__ void split_pk(float a, float b, unsigned &hi, unsigned &lo) {
    const unsigned ua = __float_as_uint(a), ub = __float_as_uint(b);
    const unsigned ha = (ua + 0x8000u) & 0xffff0000u;
    const unsigned hb = (ub + 0x8000u) & 0xffff0000u;
    hi = (ha >> 16) | hb;
    const float la = a - __uint_as_float(ha);
    const float lb = b - __uint_as_float(hb);
    lo = ((__float_as_uint(la) + 0x8000u) >> 16) |
         ((__float_as_uint(lb) + 0x8000u) & 0xffff0000u);
}

// k split into 12-bit hi + residual so kh*p (p integer, |p|<=96) is EXACT in fp32;
// phase reduced mod 1 revolution with ~2^-25 rev error.
__device__ __forceinline__ void ksplit(float k, float &kh, float &kl) {
    const unsigned u = __float_as_uint(k) & 0xfffff000u;
    kh = __uint_as_float(u);
    kl = k - kh;
}
__device__ __forceinline__ float redphase(float kh, float kl, float p) {
    float r = kh * p;
    r -= rintf(r);          // exact (kh*p exact, rndne exact)
    r = fmaf(kl, p, r);     // |r| <= ~0.512 revolutions
    return r;
}

// ---------------------------------------------------------------------------
// Adjoint: out[x,y] += sum_m conj(A[m,x]) * d[m] * conj(B[m,y])
// MFMA form: D[x][y] = sum_K S[K][x]*P[K][y] (re) / S*Q (im), K = 2m + {re,im}
// S[2m]=cos, S[2m+1]=-sin ; P[2m]=u_re, P[2m+1]=u_im ; Q = (u_im, -u_re)
// Per wave: full 48x48 tile (3x3 MFMA subtiles), K split 128 ways; the 4 waves
// of a block cover 4 consecutive splits and reduce in LDS before global atomics.
__global__ __launch_bounds__(256) void adj_mfma_k(
    const float* __restrict__ traj,
    const float* __restrict__ dre, const float* __restrict__ dim_,
    float* __restrict__ outRe, float* __restrict__ outIm)
{
    __shared__ float red[2 * 48 * 48];
    const int tid = threadIdx.x;
    const int lane = tid & 63, wid = tid >> 6;
    const int l15 = lane & 15, q = lane >> 4;
    const int tile = blockIdx.x;                 // 0..15 (4x4 of 48x48)
    const int tx = (tile & 3) * 48, ty = (tile >> 2) * 48;
    const int s = blockIdx.y * 4 + wid;          // split 0..127

    f32x4 accRe[3][3], accIm[3][3];
    #pragma unroll
    for (int i = 0; i < 3; ++i)
        #pragma unroll
        for (int j = 0; j < 3; ++j) {
            accRe[i][j] = (f32x4){0.f, 0.f, 0.f, 0.f};
            accIm[i][j] = (f32x4){0.f, 0.f, 0.f, 0.f};
        }

    float px[3], py[3];
    #pragma unroll
    for (int i = 0; i < 3; ++i) {
        px[i] = (float)(tx + i * 16 + l15 - 96);
        py[i] = (float)(ty + i * 16 + l15 - 96);
    }

    for (int ch = 0; ch < ADJ_CHUNKS; ++ch) {
        const int mb = s * MPS + ch * 16 + q * 4;     // this lane's 4 m values
        float kxh[4], kxl[4], kyh[4], kyl[4], drv[4], div[4];
        #pragma unroll
        for (int r = 0; r < 4; ++r) {
            const float2 kk = *(const float2*)(traj + 2 * (mb + r));
            ksplit(kk.x, kxh[r], kxl[r]);
            ksplit(kk.y, kyh[r], kyl[r]);
            drv[r] = dre[mb + r];
            div[r] = dim_[mb + r];
        }
        // A-operand fragments (rows = x), synthesized in registers
        u32x4 Ah[3], Al[3];
        #pragma unroll
        for (int si = 0; si < 3; ++si) {
            #pragma unroll
            for (int r = 0; r < 4; ++r) {
                const float ph = redphase(kxh[r], kxl[r], px[si]);
                const float c = __builtin_amdgcn_cosf(ph);
                const float sn = __builtin_amdgcn_sinf(ph);
                unsigned h, l;
                split_pk(c, -sn, h, l);       // (Ar, Ai) = (cos, -sin)
                Ah[si][r] = h; Al[si][r] = l;
            }
        }
        #pragma unroll
        for (int sj = 0; sj < 3; ++sj) {
            u32x4 Ph, Pl, Qh, Ql;
            #pragma unroll
            for (int r = 0; r < 4; ++r) {
                const float ph = redphase(kyh[r], kyl[r], py[sj]);
                const float c = __builtin_amdgcn_cosf(ph);
                const float sn = __builtin_amdgcn_sinf(ph);
                // u = d * conj(B), B = (cos, -sin):  u_re = dr*c - di*s ; u_im = di*c + dr*s
                const float ur = drv[r] * c - div[r] * sn;
                const float ui = div[r] * c + drv[r] * sn;
                unsigned h, l;
                split_pk(ur, ui, h, l);
                Ph[r] = h; Pl[r] = l;
                // Q = (u_im, -u_re): rotate 16, negate high half
                Qh[r] = __builtin_amdgcn_alignbit(h, h, 16) ^ 0x80000000u;
                Ql[r] = __builtin_amdgcn_alignbit(l, l, 16) ^ 0x80000000u;
            }
            #pragma unroll
            for (int si = 0; si < 3; ++si) {
                accRe[si][sj] = mfma_bf16(Ah[si], Ph, accRe[si][sj]);
                accRe[si][sj] = mfma_bf16(Ah[si], Pl, accRe[si][sj]);
                accRe[si][sj] = mfma_bf16(Al[si], Ph, accRe[si][sj]);
                accIm[si][sj] = mfma_bf16(Ah[si], Qh, accIm[si][sj]);
                accIm[si][sj] = mfma_bf16(Ah[si], Ql, accIm[si][sj]);
                accIm[si][sj] = mfma_bf16(Al[si], Qh, accIm[si][sj]);
            }
        }
    }

    // 4-way split reduction in LDS, then one global atomic per element per block
    for (int e = tid; e < 4608; e += 256) red[e] = 0.f;
    __syncthreads();
    #pragma unroll
    for (int si = 0; si < 3; ++si)
        #pragma unroll
        for (int sj = 0; sj < 3; ++sj)
            #pragma unroll
            for (int rg = 0; rg < 4; ++rg) {
                const int xl = si * 16 + q * 4 + rg;   // C/D row = quad*4+reg
                const int yl = sj * 16 + l15;          // C/D col = lane&15
                atomicAdd(&red[xl * 48 + yl], accRe[si][sj][rg]);
                atomicAdd(&red[2304 + xl * 48 + yl], accIm[si][sj][rg]);
            }
    __syncthreads();
    for (int e = tid; e < 4608; e += 256) {
        const int plane = e / 2304;
        const int rem = e - plane * 2304;
        const int xl = rem / 48, yl = rem - (rem / 48) * 48;
        float* dst = plane ? outIm : outRe;
        atomicAdd(dst + (tx + xl) * NPIX + (ty + yl), red[e]);
    }
}

// ---------------------------------------------------------------------------
// Fused forward NUFFT + row-dot:  q[m] = sum_x A[m,x] * (sum_y B[m,y]*g[x,y])
// t-GEMM: D[x][m] = sum_K G[K][x]*P[K][m], K = 2y+{re,im}. G is the pre-split
// packed image (hi/lo), read straight into A-fragments from global (L2-hot,
// 294 KB). B phasors synthesized per lane. t stays in accumulators; q reduced
// via shuffles -> no t array, no atomics. If useW: scale by |w| (final d).
__global__ __launch_bounds__(256) void fwdq_k(
    const float* __restrict__ traj,
    const unsigned* __restrict__ Ghi, const unsigned* __restrict__ Glo,
    const float* __restrict__ wre, const float* __restrict__ wim,
    const int useW,
    float* __restrict__ qre, float* __restrict__ qim)
{
    const int tid = threadIdx.x;
    const int lane = tid & 63, wid = tid >> 6;
    const int l15 = lane & 15, q = lane >> 4;
    const int m = (blockIdx.x * 4 + wid) * 16 + l15;   // this lane's sample
    const float2 kk = *(const float2*)(traj + 2 * m);
    float kxh, kxl, kyh, kyl;
    ksplit(kk.x, kxh, kxl);
    ksplit(kk.y, kyh, kyl);

    f32x4 tre[12], tim[12];
    #pragma unroll
    for (int i = 0; i < 12; ++i) {
        tre[i] = (f32x4){0.f, 0.f, 0.f, 0.f};
        tim[i] = (f32x4){0.f, 0.f, 0.f, 0.f};
    }

    for (int ch = 0; ch < 12; ++ch) {                  // K = 384 = 12 x 32
        u32x4 Ph, Pl, Qh, Ql;
        #pragma unroll
        for (int r = 0; r < 4; ++r) {
            const float py = (float)(ch * 16 + q * 4 + r - 96);
            const float ph = redphase(kyh, kyl, py);
            const float c = __builtin_amdgcn_cosf(ph);
            const float sn = __builtin_amdgcn_sinf(ph);
            // P = (br, -bi) = (cos, sin) ; Q = (bi, br) = (-sin, cos)
            unsigned h, l;
            split_pk(c, sn, h, l);
            Ph[r] = h; Pl[r] = l;
            Qh[r] = __builtin_amdgcn_alignbit(h, h, 16) ^ 0x00008000u;
            Ql[r] = __builtin_amdgcn_alignbit(l, l, 16) ^ 0x00008000u;
        }
        const int koff = ch * 16 + q * 4;
        #pragma unroll
        for (int si = 0; si < 12; ++si) {
            const int x = si * 16 + l15;               // A-frag row = lane&15
            const u32x4 gh = *(const u32x4*)(Ghi + x * NPIX + koff);
            const u32x4 gl = *(const u32x4*)(Glo + x * NPIX + koff);
            tre[si] = mfma_bf16(gh, Ph, tre[si]);
            tre[si] = mfma_bf16(gh, Pl, tre[si]);
            tre[si] = mfma_bf16(gl, Ph, tre[si]);
            tim[si] = mfma_bf16(gh, Qh, tim[si]);
            tim[si] = mfma_bf16(gh, Ql, tim[si]);
            tim[si] = mfma_bf16(gl, Qh, tim[si]);
        }
    }

    // q[m] = sum_x A[m,x]*t[m,x], A = (cos, -sin): qr = c*tr + s*ti ; qi = c*ti - s*tr
    float qr = 0.f, qi = 0.f;
    #pragma unroll
    for (int si = 0; si < 12; ++si)
        #pragma unroll
        for (int rg = 0; rg < 4; ++rg) {
            const float pxv = (float)(si * 16 + q * 4 + rg - 96);  // C/D row
            const float ph = redphase(kxh, kxl, pxv);
            const float c = __builtin_amdgcn_cosf(ph);
            const float sn = __builtin_amdgcn_sinf(ph);
            const float tr = tre[si][rg], ti = tim[si][rg];
            qr += c * tr + sn * ti;
            qi += c * ti - sn * tr;
        }
    qr += __shfl_xor(qr, 16); qi += __shfl_xor(qi, 16);
    qr += __shfl_xor(qr, 32); qi += __shfl_xor(qi, 32);
    if (lane < 16) {
        float scale = 1.f;
        if (useW) scale = sqrtf(wre[m] * wre[m] + wim[m] * wim[m]);
        qre[m] = qr * scale;
        qim[m] = qi * scale;
    }
}

// ---------------------------------------------------------------------------
__global__ void presplit_k(const float* __restrict__ re, const float* __restrict__ im,
                           unsigned* __restrict__ Gh, unsigned* __restrict__ Gl) {
    const int e = blockIdx.x * 256 + threadIdx.x;
    unsigned h, l;
    split_pk(re[e], im[e], h, l);     // low16 = re (even K), high16 = im (odd K)
    Gh[e] = h; Gl[e] = l;
}

__global__ void winit_k(float* __restrict__ wr, float* __restrict__ wi) {
    const int m = blockIdx.x * 256 + threadIdx.x;
    wr[m] = 1.f; wi[m] = 0.f;
}

__global__ void wupdate_k(float* __restrict__ wr, float* __restrict__ wi,
                          const float* __restrict__ qre, const float* __restrict__ qim) {
    const int m = blockIdx.x * 256 + threadIdx.x;
    const float den = fmaxf(sqrtf(qre[m] * qre[m] + qim[m] * qim[m]), 1e-20f);
    wr[m] /= den; wi[m] /= den;
}

// ---------------------------------------------------------------------------
extern "C" void kernel_launch(void* const* d_in, const int* in_sizes, int n_in,
                              void* d_out, int out_size, void* d_ws, size_t ws_size,
                              hipStream_t stream)
{
    const float* xin  = (const float*)d_in[0];   // (2,192,192)
    const float* traj = (const float*)d_in[1];   // (36864,2)
    float* out = (float*)d_out;                  // (2,192,192)

    float* p = (float*)d_ws;
    float* ImRe = p; p += MTOT;    // ImRe+ImIm contiguous (single memset)
    float* ImIm = p; p += MTOT;
    float* wr   = p; p += MTOT;
    float* wi   = p; p += MTOT;
    float* qre  = p; p += MTOT;
    float* qim  = p; p += MTOT;
    float* dre  = p; p += MTOT;
    float* dim_ = p; p += MTOT;
    unsigned* Ghi = (unsigned*)p; p += MTOT;
    unsigned* Glo = (unsigned*)p; p += MTOT;

    winit_k<<<MTOT / 256, 256, 0, stream>>>(wr, wi);

    for (int it = 0; it < 3; ++it) {
        hipMemsetAsync(ImRe, 0, 2 * MTOT * sizeof(float), stream);
        adj_mfma_k<<<dim3(16, SPLITS / 4), 256, 0, stream>>>(traj, wr, wi, ImRe, ImIm);
        presplit_k<<<MTOT / 256, 256, 0, stream>>>(ImRe, ImIm, Ghi, Glo);
        fwdq_k<<<MTOT / 64, 256, 0, stream>>>(traj, Ghi, Glo, nullptr, nullptr, 0, qre, qim);
        wupdate_k<<<MTOT / 256, 256, 0, stream>>>(wr, wi, qre, qim);
    }

    presplit_k<<<MTOT / 256, 256, 0, stream>>>(xin, xin + MTOT, Ghi, Glo);
    fwdq_k<<<MTOT / 64, 256, 0, stream>>>(traj, Ghi, Glo, wr, wi, 1, dre, dim_);
    hipMemsetAsync(out, 0, 2 * MTOT * sizeof(float), stream);
    adj_mfma_k<<<dim3(16, SPLITS / 4), 256, 0, stream>>>(traj, dre, dim_, out, out + MTOT);
}

// Round 3
// 776.918 us; speedup vs baseline: 2.0815x; 1.0715x over previous
//
#include <hip/hip_runtime.h>
#include <math.h>

// Radial NUFFT + Pipe-Menon density compensation, MI355X (gfx950).
// bf16 MFMA (16x16x32) with 2-term hi/lo split everywhere; phasors synthesized
// in registers via v_sin/v_cos (revolutions) + angle-addition rotor chains.
// fwdq: image staged through double-buffered LDS shared by 9 waves/block.

#define MTOT 36864      // N_SHOTS*N_SAMPLES == NPIX*NPIX
#define NPIX 192
#define SPLITS 256
#define MPS (MTOT / SPLITS)     // 144 m per split
#define ADJ_CHUNKS (MPS / 16)   // 9 chunks of 32 K

typedef __attribute__((ext_vector_type(8))) short s16x8;
typedef __attribute__((ext_vector_type(4))) float f32x4;
typedef __attribute__((ext_vector_type(4))) unsigned u32x4;

__device__ __forceinline__ f32x4 mfma_bf16(u32x4 a, u32x4 b, f32x4 c) {
    return __builtin_amdgcn_mfma_f32_16x16x32_bf16(
        __builtin_bit_cast(s16x8, a), __builtin_bit_cast(s16x8, b), c, 0, 0, 0);
}

// Split (a,b) into packed bf16 pairs: hi = (bf16(a) | bf16(b)<<16), lo = residuals.
__device__ __forceinline__ void split_pk(float a, float b, unsigned &hi, unsigned &lo) {
    const unsigned ua = __float_as_uint(a), ub = __float_as_uint(b);
    const unsigned ha = (ua + 0x8000u) & 0xffff0000u;
    const unsigned hb = (ub + 0x8000u) & 0xffff0000u;
    hi = (ha >> 16) | hb;
    const float la = a - __uint_as_float(ha);
    const float lb = b - __uint_as_float(hb);
    lo = ((__float_as_uint(la) + 0x8000u) >> 16) |
         ((__float_as_uint(lb) + 0x8000u) & 0xffff0000u);
}

// k split into 12-bit hi + residual so kh*p (p integer, |p|<=96) is EXACT in fp32.
__device__ __forceinline__ void ksplit(float k, float &kh, float &kl) {
    kh = __uint_as_float(__float_as_uint(k) & 0xfffff000u);
    kl = k - kh;
}
__device__ __forceinline__ float redphase(float kh, float kl, float p) {
    float r = kh * p;
    r -= rintf(r);
    r = fmaf(kl, p, r);
    return r;                   // revolutions, |r| <= ~0.512
}
__device__ __forceinline__ unsigned rot16(unsigned v) {
    return __builtin_amdgcn_alignbit(v, v, 16);
}

// ---------------------------------------------------------------------------
// Adjoint: out[x,y] += sum_m conj(A[m,x]) * d[m] * conj(B[m,y])
// 48x48 tile per wave (3x3 MFMA subtiles); 8 waves = 8 K-splits per block,
// LDS-reduced, then one global atomic per element per block.
// Phasors: one sincos pair per (r,side) + rotor e^{±i2pi*16k} chain over si/sj.
__global__ __launch_bounds__(512) void adj_mfma_k(
    const float* __restrict__ traj,
    const float* __restrict__ dre, const float* __restrict__ dim_,
    float* __restrict__ outRe, float* __restrict__ outIm)
{
    __shared__ float red[2 * 48 * 48];
    const int tid = threadIdx.x;
    const int lane = tid & 63, wid = tid >> 6;     // wid 0..7
    const int l15 = lane & 15, q = lane >> 4;
    const int tile = blockIdx.x;                   // 0..15 (4x4 of 48x48)
    const int tx = (tile & 3) * 48, ty = (tile >> 2) * 48;
    const int s = blockIdx.y * 8 + wid;            // split 0..255

    f32x4 accRe[3][3], accIm[3][3];
    #pragma unroll
    for (int i = 0; i < 3; ++i)
        #pragma unroll
        for (int j = 0; j < 3; ++j) {
            accRe[i][j] = (f32x4){0.f, 0.f, 0.f, 0.f};
            accIm[i][j] = (f32x4){0.f, 0.f, 0.f, 0.f};
        }

    const float pxA = (float)(tx + l15 - 96);
    const float pyB = (float)(ty + l15 - 96);

    for (int ch = 0; ch < ADJ_CHUNKS; ++ch) {
        const int mb = s * MPS + ch * 16 + q * 4;
        u32x4 Ah[3], Al[3];
        float ur[4], ui[4], ryc[4], rys[4];
        #pragma unroll
        for (int r = 0; r < 4; ++r) {
            const float2 kk = *(const float2*)(traj + 2 * (mb + r));
            const float dr_ = dre[mb + r], di_ = dim_[mb + r];
            float kh, kl;
            ksplit(kk.x, kh, kl);
            float ph = redphase(kh, kl, pxA);
            float ca = __builtin_amdgcn_cosf(ph), sa = __builtin_amdgcn_sinf(ph);
            float g = kk.x * 16.f; g -= rintf(g);
            const float rcx = __builtin_amdgcn_cosf(g), rsx = __builtin_amdgcn_sinf(g);
            #pragma unroll
            for (int si = 0; si < 3; ++si) {
                unsigned h, l; split_pk(ca, -sa, h, l);   // A = (cos, -sin)
                Ah[si][r] = h; Al[si][r] = l;
                const float nc = ca * rcx - sa * rsx, ns = sa * rcx + ca * rsx;
                ca = nc; sa = ns;
            }
            ksplit(kk.y, kh, kl);
            ph = redphase(kh, kl, pyB);
            const float cb = __builtin_amdgcn_cosf(ph), sb = __builtin_amdgcn_sinf(ph);
            // u = d*conj(B): u_re = dr*c - di*s ; u_im = di*c + dr*s
            ur[r] = dr_ * cb - di_ * sb;
            ui[r] = di_ * cb + dr_ * sb;
            g = kk.y * 16.f; g -= rintf(g);
            ryc[r] = __builtin_amdgcn_cosf(g); rys[r] = __builtin_amdgcn_sinf(g);
        }
        #pragma unroll
        for (int sj = 0; sj < 3; ++sj) {
            u32x4 Ph, Pl, Qh, Ql;
            #pragma unroll
            for (int r = 0; r < 4; ++r) {
                unsigned h, l; split_pk(ur[r], ui[r], h, l);
                Ph[r] = h; Pl[r] = l;
                Qh[r] = rot16(h) ^ 0x80000000u;           // (u_im, -u_re)
                Ql[r] = rot16(l) ^ 0x80000000u;
                // u advances by e^{+i2pi*16ky} (conj(B) has +i)
                const float nr = ur[r] * ryc[r] - ui[r] * rys[r];
                const float ni = ui[r] * ryc[r] + ur[r] * rys[r];
                ur[r] = nr; ui[r] = ni;
            }
            #pragma unroll
            for (int si = 0; si < 3; ++si) {
                accRe[si][sj] = mfma_bf16(Ah[si], Ph, accRe[si][sj]);
                accRe[si][sj] = mfma_bf16(Ah[si], Pl, accRe[si][sj]);
                accRe[si][sj] = mfma_bf16(Al[si], Ph, accRe[si][sj]);
                accIm[si][sj] = mfma_bf16(Ah[si], Qh, accIm[si][sj]);
                accIm[si][sj] = mfma_bf16(Ah[si], Ql, accIm[si][sj]);
                accIm[si][sj] = mfma_bf16(Al[si], Qh, accIm[si][sj]);
            }
        }
    }

    for (int e = tid; e < 4608; e += 512) red[e] = 0.f;
    __syncthreads();
    #pragma unroll
    for (int si = 0; si < 3; ++si)
        #pragma unroll
        for (int sj = 0; sj < 3; ++sj)
            #pragma unroll
            for (int rg = 0; rg < 4; ++rg) {
                const int xl = si * 16 + q * 4 + rg;   // C/D row = quad*4+reg
                const int yl = sj * 16 + l15;          // C/D col = lane&15
                atomicAdd(&red[xl * 48 + yl], accRe[si][sj][rg]);
                atomicAdd(&red[2304 + xl * 48 + yl], accIm[si][sj][rg]);
            }
    __syncthreads();
    for (int e = tid; e < 4608; e += 512) {
        const int plane = e / 2304;
        const int rem = e - plane * 2304;
        const int xl = rem / 48, yl = rem - (rem / 48) * 48;
        float* dst = plane ? outIm : outRe;
        atomicAdd(dst + (tx + xl) * NPIX + (ty + yl), red[e]);
    }
}

// ---------------------------------------------------------------------------
// fwdq: q[m] = sum_x A[m,x] * (sum_y B[m,y]*g[x,y]).
// 256 blocks x 9 waves (1 block/CU, no tail). G chunks (16 u32-words of K for
// all 192 x-rows, hi+lo) staged in double-buffered LDS (pad-20 rows), shared
// by all 9 waves; next chunk's global loads issued before the MFMA loop.
// mode 0: w <- w/max(|q|,1e-20) (Pipe iteration). mode 1: d = q*|w|.
__device__ __forceinline__ void fw_stage_load(const unsigned* __restrict__ Ghi,
                                              const unsigned* __restrict__ Glo,
                                              int tid, int koff, u32x4 st[3]) {
    #pragma unroll
    for (int j = 0; j < 3; ++j) {
        const int li = tid + j * 576;
        if (li < 1536) {
            const int row = li >> 3, pl = (li >> 2) & 1, qt = li & 3;
            const unsigned* src = pl ? Glo : Ghi;
            st[j] = *(const u32x4*)(src + row * 192 + koff + qt * 4);
        }
    }
}
__device__ __forceinline__ void fw_stage_write(unsigned* sb, int tid, const u32x4 st[3]) {
    #pragma unroll
    for (int j = 0; j < 3; ++j) {
        const int li = tid + j * 576;
        if (li < 1536) {
            const int row = li >> 3, pl = (li >> 2) & 1, qt = li & 3;
            *(u32x4*)(sb + pl * 3840 + row * 20 + qt * 4) = st[j];
        }
    }
}

__global__ __launch_bounds__(576) void fwdq_k(
    const float* __restrict__ traj,
    const unsigned* __restrict__ Ghi, const unsigned* __restrict__ Glo,
    float* __restrict__ wre, float* __restrict__ wim,
    const int mode,
    float* __restrict__ qre, float* __restrict__ qim)
{
    __shared__ unsigned sG[2][2 * 3840];   // 60 KB
    const int tid = threadIdx.x;
    const int lane = tid & 63, wid = tid >> 6;         // wid 0..8
    const int l15 = lane & 15, q = lane >> 4;
    const int m = (blockIdx.x * 9 + wid) * 16 + l15;
    const float2 kk = *(const float2*)(traj + 2 * m);
    float kxh, kxl, kyh, kyl;
    ksplit(kk.x, kxh, kxl);
    ksplit(kk.y, kyh, kyl);

    f32x4 tre[12], tim[12];
    #pragma unroll
    for (int i = 0; i < 12; ++i) {
        tre[i] = (f32x4){0.f, 0.f, 0.f, 0.f};
        tim[i] = (f32x4){0.f, 0.f, 0.f, 0.f};
    }

    // B-phasor rotor chain state: base at py = q*4-96; rot1 = e(ky); rot16 = e(16ky)
    float bc, bs;
    { const float ph = redphase(kyh, kyl, (float)(q * 4 - 96)); 
      bc = __builtin_amdgcn_cosf(ph); bs = __builtin_amdgcn_sinf(ph); }
    const float r1c = __builtin_amdgcn_cosf(kk.y), r1s = __builtin_amdgcn_sinf(kk.y);
    float r16c, r16s;
    { float g = kk.y * 16.f; g -= rintf(g);
      r16c = __builtin_amdgcn_cosf(g); r16s = __builtin_amdgcn_sinf(g); }

    u32x4 st[3];
    fw_stage_load(Ghi, Glo, tid, 0, st);
    fw_stage_write(&sG[0][0], tid, st);
    __syncthreads();

    for (int ch = 0; ch < 12; ++ch) {
        if (ch < 11) fw_stage_load(Ghi, Glo, tid, (ch + 1) * 16, st);

        // P = (cos, sin); Q = (-sin, cos)  [B = (cos,-sin), K-interleaved re/im]
        u32x4 Ph, Pl, Qh, Ql;
        {
            float c = bc, s = bs;
            #pragma unroll
            for (int r = 0; r < 4; ++r) {
                unsigned h, l; split_pk(c, s, h, l);
                Ph[r] = h; Pl[r] = l;
                Qh[r] = rot16(h) ^ 0x00008000u;
                Ql[r] = rot16(l) ^ 0x00008000u;
                const float nc = c * r1c - s * r1s, ns = s * r1c + c * r1s;
                c = nc; s = ns;
            }
            const float nbc = bc * r16c - bs * r16s, nbs = bs * r16c + bc * r16s;
            bc = nbc; bs = nbs;
        }

        const unsigned* sb = &sG[ch & 1][0];
        #pragma unroll
        for (int si = 0; si < 12; ++si) {
            const int base = (si * 16 + l15) * 20 + q * 4;
            const u32x4 gh = *(const u32x4*)(sb + base);
            const u32x4 gl = *(const u32x4*)(sb + 3840 + base);
            tre[si] = mfma_bf16(gh, Ph, tre[si]);
            tre[si] = mfma_bf16(gh, Pl, tre[si]);
            tre[si] = mfma_bf16(gl, Ph, tre[si]);
            tim[si] = mfma_bf16(gh, Qh, tim[si]);
            tim[si] = mfma_bf16(gh, Ql, tim[si]);
            tim[si] = mfma_bf16(gl, Qh, tim[si]);
        }

        if (ch < 11) {
            __syncthreads();
            fw_stage_write(&sG[(ch + 1) & 1][0], tid, st);
            __syncthreads();
        }
    }

    // phase 2: q[m] = sum_x A[m,x]*t[m,x], A = (cos,-sin); rotor over si (+16)
    float qr = 0.f, qi = 0.f;
    {
        float g = kk.x * 16.f; g -= rintf(g);
        const float rc = __builtin_amdgcn_cosf(g), rs = __builtin_amdgcn_sinf(g);
        #pragma unroll
        for (int rg = 0; rg < 4; ++rg) {
            const float ph = redphase(kxh, kxl, (float)(q * 4 + rg - 96));
            float c = __builtin_amdgcn_cosf(ph), s = __builtin_amdgcn_sinf(ph);
            #pragma unroll
            for (int si = 0; si < 12; ++si) {
                const float tr = tre[si][rg], ti = tim[si][rg];
                qr += c * tr + s * ti;
                qi += c * ti - s * tr;
                const float nc = c * rc - s * rs, ns = s * rc + c * rs;
                c = nc; s = ns;
            }
        }
    }
    qr += __shfl_xor(qr, 16); qi += __shfl_xor(qi, 16);
    qr += __shfl_xor(qr, 32); qi += __shfl_xor(qi, 32);
    if (lane < 16) {
        if (mode == 0) {
            const float den = fmaxf(sqrtf(qr * qr + qi * qi), 1e-20f);
            wre[m] /= den; wim[m] /= den;
        } else {
            const float sc = sqrtf(wre[m] * wre[m] + wim[m] * wim[m]);
            qre[m] = qr * sc; qim[m] = qi * sc;
        }
    }
}

// ---------------------------------------------------------------------------
__global__ void presplit_k(const float* __restrict__ re, const float* __restrict__ im,
                           unsigned* __restrict__ Gh, unsigned* __restrict__ Gl) {
    const int e = blockIdx.x * 256 + threadIdx.x;
    unsigned h, l;
    split_pk(re[e], im[e], h, l);     // low16 = re (even K), high16 = im (odd K)
    Gh[e] = h; Gl[e] = l;
}

__global__ void winit_k(float* __restrict__ wr, float* __restrict__ wi) {
    const int m = blockIdx.x * 256 + threadIdx.x;
    wr[m] = 1.f; wi[m] = 0.f;
}

// ---------------------------------------------------------------------------
extern "C" void kernel_launch(void* const* d_in, const int* in_sizes, int n_in,
                              void* d_out, int out_size, void* d_ws, size_t ws_size,
                              hipStream_t stream)
{
    const float* xin  = (const float*)d_in[0];   // (2,192,192)
    const float* traj = (const float*)d_in[1];   // (36864,2)
    float* out = (float*)d_out;                  // (2,192,192)

    float* p = (float*)d_ws;
    float* ImRe = p; p += MTOT;    // ImRe+ImIm contiguous (single memset)
    float* ImIm = p; p += MTOT;
    float* wr   = p; p += MTOT;
    float* wi   = p; p += MTOT;
    float* dre  = p; p += MTOT;
    float* dim_ = p; p += MTOT;
    unsigned* Ghi = (unsigned*)p; p += MTOT;
    unsigned* Glo = (unsigned*)p; p += MTOT;

    winit_k<<<MTOT / 256, 256, 0, stream>>>(wr, wi);

    for (int it = 0; it < 3; ++it) {
        hipMemsetAsync(ImRe, 0, 2 * MTOT * sizeof(float), stream);
        adj_mfma_k<<<dim3(16, SPLITS / 8), 512, 0, stream>>>(traj, wr, wi, ImRe, ImIm);
        presplit_k<<<MTOT / 256, 256, 0, stream>>>(ImRe, ImIm, Ghi, Glo);
        fwdq_k<<<256, 576, 0, stream>>>(traj, Ghi, Glo, wr, wi, 0, dre, dim_);
    }

    presplit_k<<<MTOT / 256, 256, 0, stream>>>(xin, xin + MTOT, Ghi, Glo);
    fwdq_k<<<256, 576, 0, stream>>>(traj, Ghi, Glo, wr, wi, 1, dre, dim_);
    hipMemsetAsync(out, 0, 2 * MTOT * sizeof(float), stream);
    adj_mfma_k<<<dim3(16, SPLITS / 8), 512, 0, stream>>>(traj, dre, dim_, out, out + MTOT);
}

// Round 5
// 761.650 us; speedup vs baseline: 2.1232x; 1.0200x over previous
//
#include <hip/hip_runtime.h>
#include <math.h>

// Radial NUFFT + Pipe-Menon density compensation, MI355X (gfx950).
// bf16 MFMA (16x16x32) with 2-term hi/lo split (3 products). Round 5 =
// round-3 structure (verified passing) + ONE change: the adjoint's A-phasor
// fragments are precomputed once to memory (packed bf16 hi/lo, fragment
// layout [x][m]) instead of sincos+rotor synthesis per chunk.

#define MTOT 36864      // N_SHOTS*N_SAMPLES == NPIX*NPIX
#define NPIX 192
#define SPLITS 256
#define MPS (MTOT / SPLITS)     // 144 m per split
#define ADJ_CHUNKS (MPS / 16)   // 9 chunks of 32 K

typedef __attribute__((ext_vector_type(8))) short s16x8;
typedef __attribute__((ext_vector_type(4))) float f32x4;
typedef __attribute__((ext_vector_type(4))) unsigned u32x4;

__device__ __forceinline__ f32x4 mfma_bf16(u32x4 a, u32x4 b, f32x4 c) {
    return __builtin_amdgcn_mfma_f32_16x16x32_bf16(
        __builtin_bit_cast(s16x8, a), __builtin_bit_cast(s16x8, b), c, 0, 0, 0);
}

// Split (a,b) into packed bf16 pairs: hi = (bf16(a) | bf16(b)<<16), lo = residuals.
__device__ __forceinline__ void split_pk(float a, float b, unsigned &hi, unsigned &lo) {
    const unsigned ua = __float_as_uint(a), ub = __float_as_uint(b);
    const unsigned ha = (ua + 0x8000u) & 0xffff0000u;
    const unsigned hb = (ub + 0x8000u) & 0xffff0000u;
    hi = (ha >> 16) | hb;
    const float la = a - __uint_as_float(ha);
    const float lb = b - __uint_as_float(hb);
    lo = ((__float_as_uint(la) + 0x8000u) >> 16) |
         ((__float_as_uint(lb) + 0x8000u) & 0xffff0000u);
}

// k split into 12-bit hi + residual so kh*p (p integer, |p|<=96) is EXACT in fp32.
__device__ __forceinline__ void ksplit(float k, float &kh, float &kl) {
    kh = __uint_as_float(__float_as_uint(k) & 0xfffff000u);
    kl = k - kh;
}
__device__ __forceinline__ float redphase(float kh, float kl, float p) {
    float r = kh * p;
    r -= rintf(r);
    r = fmaf(kl, p, r);
    return r;                   // revolutions, |r| <= ~0.512
}
__device__ __forceinline__ unsigned rot16(unsigned v) {
    return __builtin_amdgcn_alignbit(v, v, 16);
}

// ---------------------------------------------------------------------------
// Precompute A = (cos, -sin) packed bf16 hi/lo in fragment layout [x][m].
__global__ void precompA_k(const float* __restrict__ traj,
                           unsigned* __restrict__ Aph, unsigned* __restrict__ Apl) {
    const int m = blockIdx.x * 256 + threadIdx.x;
    const int x = blockIdx.y;
    float kh, kl; ksplit(traj[2 * m], kh, kl);
    const float ph = redphase(kh, kl, (float)(x - 96));
    const float c = __builtin_amdgcn_cosf(ph);
    const float s = __builtin_amdgcn_sinf(ph);
    unsigned h, l; split_pk(c, -s, h, l);
    Aph[(size_t)x * MTOT + m] = h;
    Apl[(size_t)x * MTOT + m] = l;
}

__global__ void winit_k(float* __restrict__ wr, float* __restrict__ wi) {
    const int m = blockIdx.x * 256 + threadIdx.x;
    wr[m] = 1.f; wi[m] = 0.f;
}

// ---------------------------------------------------------------------------
// Adjoint: out[x,y] += sum_m conj(A[m,x]) * d[m] * conj(B[m,y])
// 48x48 tile per wave (3x3 MFMA subtiles); 8 waves = 8 K-splits per block,
// LDS-reduced, then one global atomic per element per block.
// A fragments: direct loads from precomputed Aph/Apl (L3-resident).
// u = d*conj(B): one sincos per r + rotor e^{+i2pi*16ky} chain over sj.
__global__ __launch_bounds__(512) void adj_mfma_k(
    const float* __restrict__ traj,
    const float* __restrict__ dre, const float* __restrict__ dim_,
    const unsigned* __restrict__ Aph, const unsigned* __restrict__ Apl,
    float* __restrict__ outRe, float* __restrict__ outIm)
{
    __shared__ float red[2 * 48 * 48];
    const int tid = threadIdx.x;
    const int lane = tid & 63, wid = tid >> 6;     // wid 0..7
    const int l15 = lane & 15, q = lane >> 4;
    const int tile = blockIdx.x;                   // 0..15 (4x4 of 48x48)
    const int tx = (tile & 3) * 48, ty = (tile >> 2) * 48;
    const int s = blockIdx.y * 8 + wid;            // split 0..255

    f32x4 accRe[3][3], accIm[3][3];
    #pragma unroll
    for (int i = 0; i < 3; ++i)
        #pragma unroll
        for (int j = 0; j < 3; ++j) {
            accRe[i][j] = (f32x4){0.f, 0.f, 0.f, 0.f};
            accIm[i][j] = (f32x4){0.f, 0.f, 0.f, 0.f};
        }

    const float pyB = (float)(ty + l15 - 96);

    for (int ch = 0; ch < ADJ_CHUNKS; ++ch) {
        const int mb = s * MPS + ch * 16 + q * 4;
        // A-operand fragments: precomputed, word r <-> m = mb + r
        u32x4 Ah[3], Al[3];
        #pragma unroll
        for (int si = 0; si < 3; ++si) {
            const size_t off = (size_t)(tx + si * 16 + l15) * MTOT + mb;
            Ah[si] = *(const u32x4*)(Aph + off);
            Al[si] = *(const u32x4*)(Apl + off);
        }
        float ur[4], ui[4], ryc[4], rys[4];
        #pragma unroll
        for (int r = 0; r < 4; ++r) {
            const float ky = traj[2 * (mb + r) + 1];
            const float dr_ = dre[mb + r], di_ = dim_[mb + r];
            float kh, kl;
            ksplit(ky, kh, kl);
            const float ph = redphase(kh, kl, pyB);
            const float cb = __builtin_amdgcn_cosf(ph), sb = __builtin_amdgcn_sinf(ph);
            // u = d*conj(B): u_re = dr*c - di*s ; u_im = di*c + dr*s
            ur[r] = dr_ * cb - di_ * sb;
            ui[r] = di_ * cb + dr_ * sb;
            float g = ky * 16.f; g -= rintf(g);
            ryc[r] = __builtin_amdgcn_cosf(g); rys[r] = __builtin_amdgcn_sinf(g);
        }
        #pragma unroll
        for (int sj = 0; sj < 3; ++sj) {
            u32x4 Ph, Pl, Qh, Ql;
            #pragma unroll
            for (int r = 0; r < 4; ++r) {
                unsigned h, l; split_pk(ur[r], ui[r], h, l);
                Ph[r] = h; Pl[r] = l;
                Qh[r] = rot16(h) ^ 0x80000000u;           // (u_im, -u_re)
                Ql[r] = rot16(l) ^ 0x80000000u;
                // u advances by e^{+i2pi*16ky} (conj(B) has +i)
                const float nr = ur[r] * ryc[r] - ui[r] * rys[r];
                const float ni = ui[r] * ryc[r] + ur[r] * rys[r];
                ur[r] = nr; ui[r] = ni;
            }
            #pragma unroll
            for (int si = 0; si < 3; ++si) {
                accRe[si][sj] = mfma_bf16(Ah[si], Ph, accRe[si][sj]);
                accRe[si][sj] = mfma_bf16(Ah[si], Pl, accRe[si][sj]);
                accRe[si][sj] = mfma_bf16(Al[si], Ph, accRe[si][sj]);
                accIm[si][sj] = mfma_bf16(Ah[si], Qh, accIm[si][sj]);
                accIm[si][sj] = mfma_bf16(Ah[si], Ql, accIm[si][sj]);
                accIm[si][sj] = mfma_bf16(Al[si], Qh, accIm[si][sj]);
            }
        }
    }

    for (int e = tid; e < 4608; e += 512) red[e] = 0.f;
    __syncthreads();
    #pragma unroll
    for (int si = 0; si < 3; ++si)
        #pragma unroll
        for (int sj = 0; sj < 3; ++sj)
            #pragma unroll
            for (int rg = 0; rg < 4; ++rg) {
                const int xl = si * 16 + q * 4 + rg;   // C/D row = quad*4+reg
                const int yl = sj * 16 + l15;          // C/D col = lane&15
                atomicAdd(&red[xl * 48 + yl], accRe[si][sj][rg]);
                atomicAdd(&red[2304 + xl * 48 + yl], accIm[si][sj][rg]);
            }
    __syncthreads();
    for (int e = tid; e < 4608; e += 512) {
        const int plane = e / 2304;
        const int rem = e - plane * 2304;
        const int xl = rem / 48, yl = rem - (rem / 48) * 48;
        float* dst = plane ? outIm : outRe;
        atomicAdd(dst + (tx + xl) * NPIX + (ty + yl), red[e]);
    }
}

// ---------------------------------------------------------------------------
// fwdq: q[m] = sum_x A[m,x] * (sum_y B[m,y]*g[x,y]).
// 256 blocks x 9 waves (1 block/CU, no tail). G chunks staged in
// double-buffered LDS (pad-20 rows), shared by all 9 waves.
// mode 0: w <- w/max(|q|,1e-20) (Pipe iteration). mode 1: d = q*|w|.
__device__ __forceinline__ void fw_stage_load(const unsigned* __restrict__ Ghi,
                                              const unsigned* __restrict__ Glo,
                                              int tid, int koff, u32x4 st[3]) {
    #pragma unroll
    for (int j = 0; j < 3; ++j) {
        const int li = tid + j * 576;
        if (li < 1536) {
            const int row = li >> 3, pl = (li >> 2) & 1, qt = li & 3;
            const unsigned* src = pl ? Glo : Ghi;
            st[j] = *(const u32x4*)(src + row * 192 + koff + qt * 4);
        }
    }
}
__device__ __forceinline__ void fw_stage_write(unsigned* sb, int tid, const u32x4 st[3]) {
    #pragma unroll
    for (int j = 0; j < 3; ++j) {
        const int li = tid + j * 576;
        if (li < 1536) {
            const int row = li >> 3, pl = (li >> 2) & 1, qt = li & 3;
            *(u32x4*)(sb + pl * 3840 + row * 20 + qt * 4) = st[j];
        }
    }
}

__global__ __launch_bounds__(576) void fwdq_k(
    const float* __restrict__ traj,
    const unsigned* __restrict__ Ghi, const unsigned* __restrict__ Glo,
    float* __restrict__ wre, float* __restrict__ wim,
    const int mode,
    float* __restrict__ qre, float* __restrict__ qim)
{
    __shared__ unsigned sG[2][2 * 3840];   // 60 KB
    const int tid = threadIdx.x;
    const int lane = tid & 63, wid = tid >> 6;         // wid 0..8
    const int l15 = lane & 15, q = lane >> 4;
    const int m = (blockIdx.x * 9 + wid) * 16 + l15;
    const float2 kk = *(const float2*)(traj + 2 * m);
    float kxh, kxl, kyh, kyl;
    ksplit(kk.x, kxh, kxl);
    ksplit(kk.y, kyh, kyl);

    f32x4 tre[12], tim[12];
    #pragma unroll
    for (int i = 0; i < 12; ++i) {
        tre[i] = (f32x4){0.f, 0.f, 0.f, 0.f};
        tim[i] = (f32x4){0.f, 0.f, 0.f, 0.f};
    }

    // B-phasor rotor chain state: base at py = q*4-96; rot1 = e(ky); rot16 = e(16ky)
    float bc, bs;
    { const float ph = redphase(kyh, kyl, (float)(q * 4 - 96)); 
      bc = __builtin_amdgcn_cosf(ph); bs = __builtin_amdgcn_sinf(ph); }
    const float r1c = __builtin_amdgcn_cosf(kk.y), r1s = __builtin_amdgcn_sinf(kk.y);
    float r16c, r16s;
    { float g = kk.y * 16.f; g -= rintf(g);
      r16c = __builtin_amdgcn_cosf(g); r16s = __builtin_amdgcn_sinf(g); }

    u32x4 st[3];
    fw_stage_load(Ghi, Glo, tid, 0, st);
    fw_stage_write(&sG[0][0], tid, st);
    __syncthreads();

    for (int ch = 0; ch < 12; ++ch) {
        if (ch < 11) fw_stage_load(Ghi, Glo, tid, (ch + 1) * 16, st);

        // P = (cos, sin); Q = (-sin, cos)  [B = (cos,-sin), K-interleaved re/im]
        u32x4 Ph, Pl, Qh, Ql;
        {
            float c = bc, s = bs;
            #pragma unroll
            for (int r = 0; r < 4; ++r) {
                unsigned h, l; split_pk(c, s, h, l);
                Ph[r] = h; Pl[r] = l;
                Qh[r] = rot16(h) ^ 0x00008000u;
                Ql[r] = rot16(l) ^ 0x00008000u;
                const float nc = c * r1c - s * r1s, ns = s * r1c + c * r1s;
                c = nc; s = ns;
            }
            const float nbc = bc * r16c - bs * r16s, nbs = bs * r16c + bc * r16s;
            bc = nbc; bs = nbs;
        }

        const unsigned* sb = &sG[ch & 1][0];
        #pragma unroll
        for (int si = 0; si < 12; ++si) {
            const int base = (si * 16 + l15) * 20 + q * 4;
            const u32x4 gh = *(const u32x4*)(sb + base);
            const u32x4 gl = *(const u32x4*)(sb + 3840 + base);
            tre[si] = mfma_bf16(gh, Ph, tre[si]);
            tre[si] = mfma_bf16(gh, Pl, tre[si]);
            tre[si] = mfma_bf16(gl, Ph, tre[si]);
            tim[si] = mfma_bf16(gh, Qh, tim[si]);
            tim[si] = mfma_bf16(gh, Ql, tim[si]);
            tim[si] = mfma_bf16(gl, Qh, tim[si]);
        }

        if (ch < 11) {
            __syncthreads();
            fw_stage_write(&sG[(ch + 1) & 1][0], tid, st);
            __syncthreads();
        }
    }

    // phase 2: q[m] = sum_x A[m,x]*t[m,x], A = (cos,-sin); rotor over si (+16)
    float qr = 0.f, qi = 0.f;
    {
        float g = kk.x * 16.f; g -= rintf(g);
        const float rc = __builtin_amdgcn_cosf(g), rs = __builtin_amdgcn_sinf(g);
        #pragma unroll
        for (int rg = 0; rg < 4; ++rg) {
            const float ph = redphase(kxh, kxl, (float)(q * 4 + rg - 96));
            float c = __builtin_amdgcn_cosf(ph), s = __builtin_amdgcn_sinf(ph);
            #pragma unroll
            for (int si = 0; si < 12; ++si) {
                const float tr = tre[si][rg], ti = tim[si][rg];
                qr += c * tr + s * ti;
                qi += c * ti - s * tr;
                const float nc = c * rc - s * rs, ns = s * rc + c * rs;
                c = nc; s = ns;
            }
        }
    }
    qr += __shfl_xor(qr, 16); qi += __shfl_xor(qi, 16);
    qr += __shfl_xor(qr, 32); qi += __shfl_xor(qi, 32);
    if (lane < 16) {
        if (mode == 0) {
            const float den = fmaxf(sqrtf(qr * qr + qi * qi), 1e-20f);
            wre[m] /= den; wim[m] /= den;
        } else {
            const float sc = sqrtf(wre[m] * wre[m] + wim[m] * wim[m]);
            qre[m] = qr * sc; qim[m] = qi * sc;
        }
    }
}

// ---------------------------------------------------------------------------
__global__ void presplit_k(const float* __restrict__ re, const float* __restrict__ im,
                           unsigned* __restrict__ Gh, unsigned* __restrict__ Gl) {
    const int e = blockIdx.x * 256 + threadIdx.x;
    unsigned h, l;
    split_pk(re[e], im[e], h, l);     // low16 = re (even K), high16 = im (odd K)
    Gh[e] = h; Gl[e] = l;
}

// ---------------------------------------------------------------------------
extern "C" void kernel_launch(void* const* d_in, const int* in_sizes, int n_in,
                              void* d_out, int out_size, void* d_ws, size_t ws_size,
                              hipStream_t stream)
{
    const float* xin  = (const float*)d_in[0];   // (2,192,192)
    const float* traj = (const float*)d_in[1];   // (36864,2)
    float* out = (float*)d_out;                  // (2,192,192)

    char* pb = (char*)d_ws;
    unsigned* Aph = (unsigned*)pb; pb += (size_t)MTOT * NPIX * 4;
    unsigned* Apl = (unsigned*)pb; pb += (size_t)MTOT * NPIX * 4;
    float* ImRe = (float*)pb; pb += MTOT * 4;    // ImRe+ImIm contiguous (one memset)
    float* ImIm = (float*)pb; pb += MTOT * 4;
    float* wr   = (float*)pb; pb += MTOT * 4;
    float* wi   = (float*)pb; pb += MTOT * 4;
    float* dre  = (float*)pb; pb += MTOT * 4;
    float* dim_ = (float*)pb; pb += MTOT * 4;
    unsigned* Ghi = (unsigned*)pb; pb += MTOT * 4;
    unsigned* Glo = (unsigned*)pb; pb += MTOT * 4;

    precompA_k<<<dim3(MTOT / 256, NPIX), 256, 0, stream>>>(traj, Aph, Apl);
    winit_k<<<MTOT / 256, 256, 0, stream>>>(wr, wi);

    for (int it = 0; it < 3; ++it) {
        hipMemsetAsync(ImRe, 0, 2 * MTOT * sizeof(float), stream);
        adj_mfma_k<<<dim3(16, SPLITS / 8), 512, 0, stream>>>(traj, wr, wi,
                                                             Aph, Apl, ImRe, ImIm);
        presplit_k<<<MTOT / 256, 256, 0, stream>>>(ImRe, ImIm, Ghi, Glo);
        fwdq_k<<<256, 576, 0, stream>>>(traj, Ghi, Glo, wr, wi, 0, dre, dim_);
    }

    presplit_k<<<MTOT / 256, 256, 0, stream>>>(xin, xin + MTOT, Ghi, Glo);
    fwdq_k<<<256, 576, 0, stream>>>(traj, Ghi, Glo, wr, wi, 1, dre, dim_);
    hipMemsetAsync(out, 0, 2 * MTOT * sizeof(float), stream);
    adj_mfma_k<<<dim3(16, SPLITS / 8), 512, 0, stream>>>(traj, dre, dim_,
                                                         Aph, Apl, out, out + MTOT);
}